// Round 3
// baseline (396.246 us; speedup 1.0000x reference)
//
#include <hip/hip_runtime.h>

// Problem constants (fixed by setup_inputs)
constexpr int kB = 256;      // batch
constexpr int kN = 128;      // seq len
constexpr int kM = 512;      // mem width
constexpr int kSlots = 15;   // his_mem slots
constexpr int kS = 16;       // slots incl. null
constexpr int kW = 1536;     // attn_W row length (d_q + M)

__device__ __forceinline__ float tanh_fast(float x)
{
    float xc = fminf(15.f, fmaxf(-15.f, x));
    float ex = __expf(2.f * xc);
    return 1.f - 2.f * __builtin_amdgcn_rcpf(ex + 1.f);
}

// ---------------------------------------------------------------------------
// Empty-slot flags + zero counters.
// ---------------------------------------------------------------------------
__global__ __launch_bounds__(256) void empty_k(
    const float* __restrict__ his_mem, const float* __restrict__ null_mem,
    int* __restrict__ flags, int* __restrict__ cnt, int* __restrict__ total)
{
    if (blockIdx.x == 0) {
        cnt[threadIdx.x] = 0;                 // kB == 256 == blockDim
        if (threadIdx.x < 16) total[threadIdx.x] = 0;
    }
    int wave = threadIdx.x >> 6;
    int lane = threadIdx.x & 63;
    int row = blockIdx.x * 4 + wave;          // 0..4095
    int b = row >> 4, s = row & 15;
    const float* p = (s < kSlots) ? his_mem + (size_t)(b * kSlots + s) * kM
                                  : null_mem + (size_t)b * kM;
    int nz = 0;
    for (int j = 0; j < kM; j += 64) nz |= (p[j + lane] != 0.f);
    unsigned long long bal = __ballot(nz);
    if (lane == 0) flags[row] = (bal != 0ull) ? 0 : 1;
}

// ---------------------------------------------------------------------------
// Filter: flag (b,t) where argmax could differ from null slot 15, write the
// default one-hot(15) log rows, and append flagged steps to a compact list.
// ---------------------------------------------------------------------------
__global__ __launch_bounds__(256) void filter_k(
    const float* __restrict__ gumbel_u, const int* __restrict__ empty0,
    float* __restrict__ out_log, unsigned char* __restrict__ amb_flags,
    int* __restrict__ cnt, int* __restrict__ total, unsigned* __restrict__ list)
{
    int idx = blockIdx.x * 256 + threadIdx.x;    // b*128 + t
    int b = idx >> 7;
    const float* up = gumbel_u + (size_t)idx * kS;
    float g[kS];
#pragma unroll
    for (int s = 0; s < kS; ++s) {
        float u = up[s];
        u = fminf(fmaxf(u, 1e-20f), 1.0f);
        g[s] = -logf(-logf(u) + 1e-20f);
    }
    float e15 = empty0[b * kS + 15] ? 1.f : 0.f;
    float rhs = g[15] + 10.f * e15 - 1.01f;      // ambiguous iff g_k+10*ek >= rhs
    bool amb = false;
#pragma unroll
    for (int s = 0; s < kSlots; ++s) {
        float ek = empty0[b * kS + s] ? 1.f : 0.f;
        amb = amb || (g[s] + 10.f * ek >= rhs);
    }
    amb_flags[idx] = amb ? 1 : 0;
    if (amb) {
        int pos = atomicAdd(total, 1);
        list[pos] = (unsigned)idx;
        atomicAdd(&cnt[b], 1);
    }
    float* lp = out_log + (size_t)idx * kS;
    float4 zz = make_float4(0.f, 0.f, 0.f, 0.f);
    *(float4*)(lp + 0) = zz;
    *(float4*)(lp + 4) = zz;
    *(float4*)(lp + 8) = zz;
    *(float4*)(lp + 12) = make_float4(0.f, 0.f, 0.f, 1.f);
}

// ---------------------------------------------------------------------------
// Bulk hm copy: out_hm = his_mem (written slots get overwritten by phaseB).
// ---------------------------------------------------------------------------
__global__ __launch_bounds__(256) void hmcopy_k(
    const float* __restrict__ his_mem, float* __restrict__ out)
{
    size_t i = ((size_t)blockIdx.x * 256 + threadIdx.x) * 4;
    *(float4*)(out + i) = *(const float4*)(his_mem + i);
}

// ---------------------------------------------------------------------------
// C0[b*16+s][m] = W[m][1024:1536] . mem[b,s] — only for batch groups with
// ambiguous steps.
// ---------------------------------------------------------------------------
__global__ __launch_bounds__(256) void c0_k(
    const float* __restrict__ W, const float* __restrict__ his_mem,
    const float* __restrict__ null_mem, const int* __restrict__ cnt,
    float* __restrict__ C0)
{
    const int r0 = blockIdx.x * 64;              // rows r = b*16+s
    const int b0 = r0 >> 4;                      // covers batches b0..b0+3
    if (cnt[b0] == 0 && cnt[b0 + 1] == 0 && cnt[b0 + 2] == 0 && cnt[b0 + 3] == 0)
        return;
    __shared__ float As[16 * 68];
    __shared__ float Bs[16 * 68];
    const int n0 = blockIdx.y * 64;
    const int tid = threadIdx.x;
    const int row_l = tid >> 2;
    const int k4 = (tid & 3) * 4;
    const int ty = tid >> 4, tx = tid & 15;

    int r = r0 + row_l;
    int b = r >> 4, s = r & 15;
    const float* ap = (s < kSlots) ? (his_mem + (size_t)(b * kSlots + s) * kM)
                                   : (null_mem + (size_t)b * kM);
    const float* wp = W + (size_t)(n0 + row_l) * kW + 1024;

    float acc[4][4];
#pragma unroll
    for (int i = 0; i < 4; ++i)
#pragma unroll
        for (int j = 0; j < 4; ++j) acc[i][j] = 0.f;

    for (int kt = 0; kt < kM; kt += 16) {
        float4 a4 = *(const float4*)(ap + kt + k4);
        float4 b4 = *(const float4*)(wp + kt + k4);
        __syncthreads();
        As[(k4 + 0) * 68 + row_l] = a4.x; As[(k4 + 1) * 68 + row_l] = a4.y;
        As[(k4 + 2) * 68 + row_l] = a4.z; As[(k4 + 3) * 68 + row_l] = a4.w;
        Bs[(k4 + 0) * 68 + row_l] = b4.x; Bs[(k4 + 1) * 68 + row_l] = b4.y;
        Bs[(k4 + 2) * 68 + row_l] = b4.z; Bs[(k4 + 3) * 68 + row_l] = b4.w;
        __syncthreads();
#pragma unroll
        for (int k = 0; k < 16; ++k) {
            const float4 av = *(const float4*)&As[k * 68 + ty * 4];
            const float4 bv = *(const float4*)&Bs[k * 68 + tx * 4];
            acc[0][0] = fmaf(av.x, bv.x, acc[0][0]);
            acc[0][1] = fmaf(av.x, bv.y, acc[0][1]);
            acc[0][2] = fmaf(av.x, bv.z, acc[0][2]);
            acc[0][3] = fmaf(av.x, bv.w, acc[0][3]);
            acc[1][0] = fmaf(av.y, bv.x, acc[1][0]);
            acc[1][1] = fmaf(av.y, bv.y, acc[1][1]);
            acc[1][2] = fmaf(av.y, bv.z, acc[1][2]);
            acc[1][3] = fmaf(av.y, bv.w, acc[1][3]);
            acc[2][0] = fmaf(av.z, bv.x, acc[2][0]);
            acc[2][1] = fmaf(av.z, bv.y, acc[2][1]);
            acc[2][2] = fmaf(av.z, bv.z, acc[2][2]);
            acc[2][3] = fmaf(av.z, bv.w, acc[2][3]);
            acc[3][0] = fmaf(av.w, bv.x, acc[3][0]);
            acc[3][1] = fmaf(av.w, bv.y, acc[3][1]);
            acc[3][2] = fmaf(av.w, bv.z, acc[3][2]);
            acc[3][3] = fmaf(av.w, bv.w, acc[3][3]);
        }
    }
#pragma unroll
    for (int i = 0; i < 4; ++i) {
        float4 o = make_float4(acc[i][0], acc[i][1], acc[i][2], acc[i][3]);
        *(float4*)(C0 + (size_t)(r0 + ty * 4 + i) * kM + n0 + tx * 4) = o;
    }
}

// ---------------------------------------------------------------------------
// Phase A: resolve every ambiguous step in parallel assuming memory == C0.
// One 512-thread block per list entry (grid-stride). Coalesced W reads:
// 16 threads cooperate per W row.
// ---------------------------------------------------------------------------
__global__ __launch_bounds__(512) void phaseA_k(
    const float* __restrict__ C0, const int* __restrict__ empty0,
    const int* __restrict__ total, const unsigned* __restrict__ list,
    const float* __restrict__ states, const float* __restrict__ global_trace,
    const float* __restrict__ W, const float* __restrict__ attn_b,
    const float* __restrict__ v, const float* __restrict__ gumbel_u,
    unsigned char* __restrict__ resK)
{
    const int n = *total;
    const int tid = threadIdx.x;
    __shared__ float Xs[1024];
    __shared__ float qs[kM];
    __shared__ float vs[kM];
    __shared__ float bs[kM];
    __shared__ float e_sh[kS];

    for (int i = blockIdx.x; i < n; i += gridDim.x) {
        const int idx = (int)list[i];
        const int b = idx >> 7;
        __syncthreads();   // protect shared reuse across grid-stride iterations
        // stage [state | global_trace], v, bias
        Xs[tid] = states[(size_t)idx * kM + (tid & 511)];
        if (tid < kM) {
            Xs[512 + tid] = global_trace[(size_t)b * kM + tid];
            vs[tid] = v[tid];
            bs[tid] = attn_b[tid];
        } else {
            int t2 = tid - 512;
            Xs[512 + t2 + 0] = Xs[512 + t2];   // no-op placeholder
        }
        // fix: threads 0..511 stage everything (blockDim==512 so all do)
        __syncthreads();

        // q[r] = bias[r] + W[r][0:1024] . Xs ; 16 threads per row, coalesced
        const int g = tid >> 4;      // 0..31 row group
        const int l = tid & 15;      // lane in group
        for (int r0 = 0; r0 < kM; r0 += 32) {
            int r = r0 + g;
            const float* wr = W + (size_t)r * kW;
            float acc = 0.f;
#pragma unroll
            for (int k = l * 4; k < 1024; k += 64) {
                float4 w4 = *(const float4*)(wr + k);
                float4 x4 = *(const float4*)&Xs[k];
                acc = fmaf(w4.x, x4.x, acc); acc = fmaf(w4.y, x4.y, acc);
                acc = fmaf(w4.z, x4.z, acc); acc = fmaf(w4.w, x4.w, acc);
            }
            acc += __shfl_xor(acc, 1); acc += __shfl_xor(acc, 2);
            acc += __shfl_xor(acc, 4); acc += __shfl_xor(acc, 8);
            if (l == 0) qs[r] = acc + bs[r];
        }
        __syncthreads();

        // e[s] = sum_m v[m] * tanh(q[m] + C0[b,s][m]); 32 lanes per slot
        const int s = tid >> 5, ml = tid & 31;
        const float* c0r = C0 + (size_t)(b * kS + s) * kM;
        float a = 0.f;
#pragma unroll
        for (int j = 0; j < 16; ++j) {
            int m = ml + j * 32;
            a = fmaf(vs[m], tanh_fast(qs[m] + c0r[m]), a);
        }
        a += __shfl_xor(a, 1); a += __shfl_xor(a, 2);
        a += __shfl_xor(a, 4); a += __shfl_xor(a, 8); a += __shfl_xor(a, 16);
        if (ml == 0) e_sh[s] = a;
        __syncthreads();

        // wave 0: softmax + empty mask + gumbel + argmax
        if (tid < 64) {
            int ss = tid;
            float ev = (ss < kS) ? e_sh[ss] : -3.0e38f;
            float mx = ev;
            mx = fmaxf(mx, __shfl_xor(mx, 1));
            mx = fmaxf(mx, __shfl_xor(mx, 2));
            mx = fmaxf(mx, __shfl_xor(mx, 4));
            mx = fmaxf(mx, __shfl_xor(mx, 8));
            float w = (ss < kS) ? __expf(ev - mx) : 0.f;
            float sm = w;
            sm += __shfl_xor(sm, 1); sm += __shfl_xor(sm, 2);
            sm += __shfl_xor(sm, 4); sm += __shfl_xor(sm, 8);
            w = w / sm;
            w += 10.0f * ((ss < kS) ? (empty0[b * kS + ss] ? 1.f : 0.f) : 0.f);
            float z;
            if (ss < kS) {
                float u = gumbel_u[(size_t)idx * kS + ss];
                u = fminf(fmaxf(u, 1e-20f), 1.0f);
                float gg = -logf(-logf(u) + 1e-20f);
                z = w + gg;
            } else z = -3.0e38f;
            float zm = z;
            zm = fmaxf(zm, __shfl_xor(zm, 1));
            zm = fmaxf(zm, __shfl_xor(zm, 2));
            zm = fmaxf(zm, __shfl_xor(zm, 4));
            zm = fmaxf(zm, __shfl_xor(zm, 8));
            unsigned long long bal = __ballot(z == zm) & 0xFFFFull;
            int k = __ffsll(bal) - 1;
            if (ss == 0) resK[idx] = (unsigned char)k;
        }
    }
}

// ---------------------------------------------------------------------------
// Phase B: per batch, walk ambiguous steps in order. Accept phase-A results
// until the first write; afterwards recompute steps exactly with updated C.
// ---------------------------------------------------------------------------
constexpr int kCsStride = 528;   // 512+16 -> at most 2-way bank aliasing (free)

__global__ __launch_bounds__(256) void phaseB_k(
    const float* __restrict__ C0, const int* __restrict__ empty0,
    const unsigned char* __restrict__ amb_flags, const int* __restrict__ cnt,
    const unsigned char* __restrict__ resK,
    const float* __restrict__ states, const float* __restrict__ states_mask,
    const float* __restrict__ gumbel_u, const float* __restrict__ global_trace,
    const float* __restrict__ W, const float* __restrict__ attn_b,
    const float* __restrict__ v, float* __restrict__ out)
{
    const int b = blockIdx.x;
    if (cnt[b] == 0) return;     // defaults already correct
    const int tid = threadIdx.x;
    float* out_hm = out;
    float* out_log = out + (size_t)kB * kSlots * kM;

    __shared__ float Cs[kS * kCsStride];
    __shared__ float Xs[1024];
    __shared__ float qs[kM];
    __shared__ float vs[kM];
    __shared__ float bs[kM];
    __shared__ float e_sh[kS];
    __shared__ float empty_sh[kS];
    __shared__ unsigned char flS[kN];
    __shared__ int slot_src[kSlots];
    __shared__ int k_sh, wk_sh, nz_sh, mod_sh;

    for (int i = tid; i < kM; i += 256) {
        vs[i] = v[i];
        bs[i] = attn_b[i];
        Xs[512 + i] = global_trace[(size_t)b * kM + i];
    }
    if (tid < kS) empty_sh[tid] = empty0[b * kS + tid] ? 1.0f : 0.0f;
    if (tid < kSlots) slot_src[tid] = -1;
    if (tid < kN) flS[tid] = amb_flags[b * kN + tid];
    if (tid == 0) mod_sh = 0;
    __syncthreads();

    const int sidx = tid >> 4;
    const int ml = tid & 15;

    for (int t = 0; t < kN; ++t) {
        if (!flS[t]) continue;

        if (mod_sh) {
            // ---- full exact recompute with current Cs ----
            Xs[tid] = states[(size_t)(b * kN + t) * kM + tid];
            Xs[tid + 256] = states[(size_t)(b * kN + t) * kM + tid + 256];
            __syncthreads();
            const float* wra = W + (size_t)tid * kW;
            const float* wrb = W + (size_t)(tid + 256) * kW;
            float qa = bs[tid], qb = bs[tid + 256];
#pragma unroll 4
            for (int k = 0; k < 1024; k += 4) {
                float4 wa = *(const float4*)(wra + k);
                float4 wb = *(const float4*)(wrb + k);
                float4 xv = *(const float4*)&Xs[k];
                qa = fmaf(wa.x, xv.x, qa); qa = fmaf(wa.y, xv.y, qa);
                qa = fmaf(wa.z, xv.z, qa); qa = fmaf(wa.w, xv.w, qa);
                qb = fmaf(wb.x, xv.x, qb); qb = fmaf(wb.y, xv.y, qb);
                qb = fmaf(wb.z, xv.z, qb); qb = fmaf(wb.w, xv.w, qb);
            }
            qs[tid] = qa; qs[tid + 256] = qb;
            __syncthreads();

            const float* crow = &Cs[sidx * kCsStride];
            float a0 = 0.f, a1 = 0.f;
#pragma unroll 8
            for (int j = 0; j < 32; ++j) {
                int m = ml + j * 16;
                float x = qs[m] + crow[m];
                float th = tanh_fast(x);
                if (j & 1) a1 = fmaf(vs[m], th, a1);
                else       a0 = fmaf(vs[m], th, a0);
            }
            float e = a0 + a1;
            e += __shfl_xor(e, 1); e += __shfl_xor(e, 2);
            e += __shfl_xor(e, 4); e += __shfl_xor(e, 8);
            if (ml == 0) e_sh[sidx] = e;
            __syncthreads();

            if (tid < 64) {
                int s = tid;
                float ev = (s < kS) ? e_sh[s] : -3.0e38f;
                float mx = ev;
                mx = fmaxf(mx, __shfl_xor(mx, 1));
                mx = fmaxf(mx, __shfl_xor(mx, 2));
                mx = fmaxf(mx, __shfl_xor(mx, 4));
                mx = fmaxf(mx, __shfl_xor(mx, 8));
                float w = (s < kS) ? __expf(ev - mx) : 0.f;
                float sm = w;
                sm += __shfl_xor(sm, 1); sm += __shfl_xor(sm, 2);
                sm += __shfl_xor(sm, 4); sm += __shfl_xor(sm, 8);
                w = w / sm;
                w += 10.0f * ((s < kS) ? empty_sh[s] : 0.f);
                float z;
                if (s < kS) {
                    float u = gumbel_u[(size_t)(b * kN + t) * kS + s];
                    u = fminf(fmaxf(u, 1e-20f), 1.0f);
                    float g = -logf(-logf(u) + 1e-20f);
                    z = w + g;
                } else z = -3.0e38f;
                float zm = z;
                zm = fmaxf(zm, __shfl_xor(zm, 1));
                zm = fmaxf(zm, __shfl_xor(zm, 2));
                zm = fmaxf(zm, __shfl_xor(zm, 4));
                zm = fmaxf(zm, __shfl_xor(zm, 8));
                unsigned long long bal = __ballot(z == zm) & 0xFFFFull;
                if (s == 0) k_sh = __ffsll(bal) - 1;
            }
            __syncthreads();
        } else {
            if (tid == 0) k_sh = resK[b * kN + t];
            __syncthreads();
        }

        const int k = k_sh;
        if (tid < kS) out_log[(size_t)(b * kN + t) * kS + tid] = (tid == k) ? 1.f : 0.f;
        if (tid == 0) {
            float mv = states_mask[b * kN + t];
            wk_sh = (k < kSlots && mv != 0.0f) ? k : -1;
            nz_sh = 0;
        }
        __syncthreads();

        const int wk = wk_sh;
        if (wk >= 0) {
            const int was_mod = mod_sh;
            if (!was_mod) {
                for (int i = tid; i < kS * kM; i += 256) {
                    int s = i >> 9, m = i & 511;
                    Cs[s * kCsStride + m] = C0[(size_t)(b * kS + s) * kM + m];
                }
            }
            float s0v = states[(size_t)(b * kN + t) * kM + tid];
            float s1v = states[(size_t)(b * kN + t) * kM + tid + 256];
            Xs[tid] = s0v; Xs[tid + 256] = s1v;
            if (s0v != 0.f || s1v != 0.f) nz_sh = 1;
            __syncthreads();

            const float* w3a = W + (size_t)tid * kW + 1024;
            const float* w3b = W + (size_t)(tid + 256) * kW + 1024;
            float ca = 0.f, cb = 0.f;
#pragma unroll 4
            for (int kk = 0; kk < kM; kk += 4) {
                float4 wa = *(const float4*)(w3a + kk);
                float4 wb = *(const float4*)(w3b + kk);
                float4 sv = *(const float4*)&Xs[kk];
                ca = fmaf(wa.x, sv.x, ca); ca = fmaf(wa.y, sv.y, ca);
                ca = fmaf(wa.z, sv.z, ca); ca = fmaf(wa.w, sv.w, ca);
                cb = fmaf(wb.x, sv.x, cb); cb = fmaf(wb.y, sv.y, cb);
                cb = fmaf(wb.z, sv.z, cb); cb = fmaf(wb.w, sv.w, cb);
            }
            Cs[wk * kCsStride + tid] = ca;
            Cs[wk * kCsStride + tid + 256] = cb;
            __syncthreads();
            if (tid == 0) {
                slot_src[wk] = t;
                empty_sh[wk] = nz_sh ? 0.f : 1.f;
                mod_sh = 1;
            }
        }
        __syncthreads();
    }

    // epilogue: overwrite written slots only (bulk copy already done)
    for (int s = 0; s < kSlots; ++s) {
        int ts = slot_src[s];
        if (ts >= 0) {
            float* dst = out_hm + (size_t)(b * kSlots + s) * kM;
            dst[tid] = states[(size_t)(b * kN + ts) * kM + tid];
            dst[tid + 256] = states[(size_t)(b * kN + ts) * kM + tid + 256];
        }
    }
}

// ---------------------------------------------------------------------------
extern "C" void kernel_launch(void* const* d_in, const int* in_sizes, int n_in,
                              void* d_out, int out_size, void* d_ws, size_t ws_size,
                              hipStream_t stream)
{
    const float* his_mem      = (const float*)d_in[0];
    const float* states       = (const float*)d_in[1];
    const float* states_mask  = (const float*)d_in[2];
    const float* global_trace = (const float*)d_in[3];
    const float* null_mem     = (const float*)d_in[4];
    const float* gumbel_u     = (const float*)d_in[5];
    const float* attn_W       = (const float*)d_in[6];
    const float* attn_b       = (const float*)d_in[7];
    const float* v            = (const float*)d_in[8];

    // ws layout: C0[4096*512] f32 | empty0[4096] i32 | cnt[256] i32 |
    //            total[16] i32 | amb[32768] u8 | list[32768] u32 | resK[32768] u8
    float* C0 = (float*)d_ws;
    int* empty0 = (int*)(C0 + (size_t)kB * kS * kM);
    int* cnt = empty0 + kB * kS;
    int* total = cnt + kB;
    unsigned char* amb = (unsigned char*)(total + 16);
    unsigned* list = (unsigned*)(amb + kB * kN);
    unsigned char* resK = (unsigned char*)(list + kB * kN);

    float* out_log = (float*)d_out + (size_t)kB * kSlots * kM;

    empty_k<<<kB * kS / 4, 256, 0, stream>>>(his_mem, null_mem, empty0, cnt, total);
    filter_k<<<kB * kN / 256, 256, 0, stream>>>(gumbel_u, empty0, out_log, amb, cnt, total, list);
    hmcopy_k<<<(kB * kSlots * kM) / (256 * 4), 256, 0, stream>>>(his_mem, (float*)d_out);
    c0_k<<<dim3(kB * kS / 64, kM / 64), 256, 0, stream>>>(attn_W, his_mem, null_mem, cnt, C0);
    phaseA_k<<<256, 512, 0, stream>>>(C0, empty0, total, list, states, global_trace,
                                      attn_W, attn_b, v, gumbel_u, resK);
    phaseB_k<<<kB, 256, 0, stream>>>(C0, empty0, amb, cnt, resK, states, states_mask,
                                     gumbel_u, global_trace, attn_W, attn_b, v,
                                     (float*)d_out);
}

// Round 4
// 273.701 us; speedup vs baseline: 1.4477x; 1.4477x over previous
//
#include <hip/hip_runtime.h>

// Problem constants (fixed by setup_inputs)
constexpr int kB = 256;      // batch
constexpr int kN = 128;      // seq len
constexpr int kM = 512;      // mem width
constexpr int kSlots = 15;   // his_mem slots
constexpr int kS = 16;       // slots incl. null
constexpr int kW = 1536;     // attn_W row length (d_q + M)

__device__ __forceinline__ float tanh_fast(float x)
{
    float xc = fminf(15.f, fmaxf(-15.f, x));
    float ex = __expf(2.f * xc);
    return 1.f - 2.f * __builtin_amdgcn_rcpf(ex + 1.f);
}

// ---------------------------------------------------------------------------
// Empty-slot flags + zero counters + bulk hm copy (out_hm = his_mem).
// One wave per slot-row; float4 reads serve both the nz-test and the copy.
// ---------------------------------------------------------------------------
__global__ __launch_bounds__(256) void emptycopy_k(
    const float* __restrict__ his_mem, const float* __restrict__ null_mem,
    float* __restrict__ out_hm, int* __restrict__ flags,
    int* __restrict__ cnt, int* __restrict__ total)
{
    if (blockIdx.x == 0) {
        cnt[threadIdx.x] = 0;                 // kB == 256 == blockDim
        if (threadIdx.x < 16) total[threadIdx.x] = 0;
    }
    int wave = threadIdx.x >> 6;
    int lane = threadIdx.x & 63;
    int row = blockIdx.x * 4 + wave;          // 0..4095
    int b = row >> 4, s = row & 15;
    const float* p = (s < kSlots) ? his_mem + (size_t)(b * kSlots + s) * kM
                                  : null_mem + (size_t)b * kM;
    float4 v0 = *(const float4*)(p + lane * 4);
    float4 v1 = *(const float4*)(p + 256 + lane * 4);
    int nz = (v0.x != 0.f) | (v0.y != 0.f) | (v0.z != 0.f) | (v0.w != 0.f) |
             (v1.x != 0.f) | (v1.y != 0.f) | (v1.z != 0.f) | (v1.w != 0.f);
    unsigned long long bal = __ballot(nz);
    if (lane == 0) flags[row] = (bal != 0ull) ? 0 : 1;
    if (s < kSlots) {
        float* dst = out_hm + (size_t)(b * kSlots + s) * kM;
        *(float4*)(dst + lane * 4) = v0;
        *(float4*)(dst + 256 + lane * 4) = v1;
    }
}

// ---------------------------------------------------------------------------
// Filter: flag (b,t) where argmax could differ from null slot 15, write the
// default one-hot(15) log rows, append to compact step list + batch list.
// ---------------------------------------------------------------------------
__global__ __launch_bounds__(256) void filter_k(
    const float* __restrict__ gumbel_u, const int* __restrict__ empty0,
    float* __restrict__ out_log, unsigned char* __restrict__ amb_flags,
    int* __restrict__ cnt, int* __restrict__ total, unsigned* __restrict__ list,
    int* __restrict__ listPos, int* __restrict__ ambBatch)
{
    int idx = blockIdx.x * 256 + threadIdx.x;    // b*128 + t
    int b = idx >> 7;
    const float* up = gumbel_u + (size_t)idx * kS;
    float g[kS];
#pragma unroll
    for (int s = 0; s < kS; ++s) {
        float u = up[s];
        u = fminf(fmaxf(u, 1e-20f), 1.0f);
        g[s] = -logf(-logf(u) + 1e-20f);
    }
    float e15 = empty0[b * kS + 15] ? 1.f : 0.f;
    float rhs = g[15] + 10.f * e15 - 1.01f;      // ambiguous iff g_k+10*ek >= rhs
    bool amb = false;
#pragma unroll
    for (int s = 0; s < kSlots; ++s) {
        float ek = empty0[b * kS + s] ? 1.f : 0.f;
        amb = amb || (g[s] + 10.f * ek >= rhs);
    }
    amb_flags[idx] = amb ? 1 : 0;
    if (amb) {
        int pos = atomicAdd(&total[0], 1);
        list[pos] = (unsigned)idx;
        listPos[idx] = pos;
        int prev = atomicAdd(&cnt[b], 1);
        if (prev == 0) {
            int bp = atomicAdd(&total[1], 1);
            ambBatch[bp] = b;
        }
    }
    float* lp = out_log + (size_t)idx * kS;
    float4 zz = make_float4(0.f, 0.f, 0.f, 0.f);
    *(float4*)(lp + 0) = zz;
    *(float4*)(lp + 4) = zz;
    *(float4*)(lp + 8) = zz;
    *(float4*)(lp + 12) = make_float4(0.f, 0.f, 0.f, 1.f);
}

// ---------------------------------------------------------------------------
// C0[b*16+s][m] = W[m][1024:1536] . mem[b,s] — gathered over the compacted
// ambiguous-batch list (4 batches = 64 rows per block.x).
// ---------------------------------------------------------------------------
__global__ __launch_bounds__(256) void c0_k(
    const float* __restrict__ W, const float* __restrict__ his_mem,
    const float* __restrict__ null_mem, const int* __restrict__ total,
    const int* __restrict__ ambBatch, float* __restrict__ C0)
{
    const int nab = total[1];
    if ((int)blockIdx.x * 4 >= nab) return;
    __shared__ float As[16 * 68];
    __shared__ float Bs[16 * 68];
    const int n0 = blockIdx.y * 64;
    const int tid = threadIdx.x;
    const int row_l = tid >> 2;
    const int k4 = (tid & 3) * 4;
    const int ty = tid >> 4, tx = tid & 15;

    int bi = blockIdx.x * 4 + (row_l >> 4);
    if (bi >= nab) bi = nab - 1;               // clamp: redundant same-value work
    const int b = ambBatch[bi];
    const int s = row_l & 15;
    const float* ap = (s < kSlots) ? (his_mem + (size_t)(b * kSlots + s) * kM)
                                   : (null_mem + (size_t)b * kM);
    const float* wp = W + (size_t)(n0 + row_l) * kW + 1024;

    float acc[4][4];
#pragma unroll
    for (int i = 0; i < 4; ++i)
#pragma unroll
        for (int j = 0; j < 4; ++j) acc[i][j] = 0.f;

    for (int kt = 0; kt < kM; kt += 16) {
        float4 a4 = *(const float4*)(ap + kt + k4);
        float4 b4 = *(const float4*)(wp + kt + k4);
        __syncthreads();
        As[(k4 + 0) * 68 + row_l] = a4.x; As[(k4 + 1) * 68 + row_l] = a4.y;
        As[(k4 + 2) * 68 + row_l] = a4.z; As[(k4 + 3) * 68 + row_l] = a4.w;
        Bs[(k4 + 0) * 68 + row_l] = b4.x; Bs[(k4 + 1) * 68 + row_l] = b4.y;
        Bs[(k4 + 2) * 68 + row_l] = b4.z; Bs[(k4 + 3) * 68 + row_l] = b4.w;
        __syncthreads();
#pragma unroll
        for (int k = 0; k < 16; ++k) {
            const float4 av = *(const float4*)&As[k * 68 + ty * 4];
            const float4 bv = *(const float4*)&Bs[k * 68 + tx * 4];
            acc[0][0] = fmaf(av.x, bv.x, acc[0][0]);
            acc[0][1] = fmaf(av.x, bv.y, acc[0][1]);
            acc[0][2] = fmaf(av.x, bv.z, acc[0][2]);
            acc[0][3] = fmaf(av.x, bv.w, acc[0][3]);
            acc[1][0] = fmaf(av.y, bv.x, acc[1][0]);
            acc[1][1] = fmaf(av.y, bv.y, acc[1][1]);
            acc[1][2] = fmaf(av.y, bv.z, acc[1][2]);
            acc[1][3] = fmaf(av.y, bv.w, acc[1][3]);
            acc[2][0] = fmaf(av.z, bv.x, acc[2][0]);
            acc[2][1] = fmaf(av.z, bv.y, acc[2][1]);
            acc[2][2] = fmaf(av.z, bv.z, acc[2][2]);
            acc[2][3] = fmaf(av.z, bv.w, acc[2][3]);
            acc[3][0] = fmaf(av.w, bv.x, acc[3][0]);
            acc[3][1] = fmaf(av.w, bv.y, acc[3][1]);
            acc[3][2] = fmaf(av.w, bv.z, acc[3][2]);
            acc[3][3] = fmaf(av.w, bv.w, acc[3][3]);
        }
    }
#pragma unroll
    for (int i = 0; i < 4; ++i) {
        int rl = ty * 4 + i;
        int bij = blockIdx.x * 4 + (rl >> 4);
        if (bij >= nab) bij = nab - 1;
        int ro = ambBatch[bij] * kS + (rl & 15);
        float4 o = make_float4(acc[i][0], acc[i][1], acc[i][2], acc[i][3]);
        *(float4*)(C0 + (size_t)ro * kM + n0 + tx * 4) = o;
    }
}

// ---------------------------------------------------------------------------
// q_k: for every ambiguous step, q[m] = bias[m] + W[m][0:1024].[state|gt],
// stored to qCache[listPos]. Coalesced: 16 lanes cooperate per W row.
// ---------------------------------------------------------------------------
__global__ __launch_bounds__(512) void q_k(
    const int* __restrict__ total, const unsigned* __restrict__ list,
    const float* __restrict__ states, const float* __restrict__ global_trace,
    const float* __restrict__ W, const float* __restrict__ attn_b,
    float* __restrict__ qCache)
{
    const int n = total[0];
    const int tid = threadIdx.x;
    __shared__ float Xs[1024];
    __shared__ float qs[kM];

    for (int i = blockIdx.x; i < n; i += gridDim.x) {
        const int idx = (int)list[i];
        const int b = idx >> 7;
        __syncthreads();   // protect shared reuse across grid-stride iterations
        Xs[tid] = states[(size_t)idx * kM + tid];
        Xs[512 + tid] = global_trace[(size_t)b * kM + tid];
        __syncthreads();

        const int g = tid >> 4;      // 0..31 row group
        const int l = tid & 15;      // lane in group
        for (int r0 = 0; r0 < kM; r0 += 32) {
            int r = r0 + g;
            const float* wr = W + (size_t)r * kW;
            float acc = 0.f;
#pragma unroll
            for (int k = l * 4; k < 1024; k += 64) {
                float4 w4 = *(const float4*)(wr + k);
                float4 x4 = *(const float4*)&Xs[k];
                acc = fmaf(w4.x, x4.x, acc); acc = fmaf(w4.y, x4.y, acc);
                acc = fmaf(w4.z, x4.z, acc); acc = fmaf(w4.w, x4.w, acc);
            }
            acc += __shfl_xor(acc, 1); acc += __shfl_xor(acc, 2);
            acc += __shfl_xor(acc, 4); acc += __shfl_xor(acc, 8);
            if (l == 0) qs[r] = acc + attn_b[r];
        }
        __syncthreads();
        qCache[(size_t)i * kM + tid] = qs[tid];
    }
}

// ---------------------------------------------------------------------------
// Phase B: per ambiguous batch, walk flagged steps in order. Each step is now
// cheap (cached q + LDS C); only an actual write pays a coalesced 512x512 GEMV.
// ---------------------------------------------------------------------------
constexpr int kCsStride = 528;   // 512+16 -> at most 2-way bank aliasing (free)

__global__ __launch_bounds__(256) void phaseB_k(
    const float* __restrict__ C0, const int* __restrict__ empty0,
    const unsigned char* __restrict__ amb_flags, const int* __restrict__ cnt,
    const int* __restrict__ listPos, const float* __restrict__ qCache,
    const float* __restrict__ states, const float* __restrict__ states_mask,
    const float* __restrict__ gumbel_u, const float* __restrict__ W,
    const float* __restrict__ v, float* __restrict__ out)
{
    const int b = blockIdx.x;
    if (cnt[b] == 0) return;     // defaults already correct
    const int tid = threadIdx.x;
    float* out_hm = out;
    float* out_log = out + (size_t)kB * kSlots * kM;

    __shared__ float Cs[kS * kCsStride];
    __shared__ float Xs[kM];
    __shared__ float vs[kM];
    __shared__ float e_sh[kS];
    __shared__ float empty_sh[kS];
    __shared__ unsigned char flS[kN];
    __shared__ int slot_src[kSlots];
    __shared__ int k_sh, wk_sh, nz_sh;

    for (int i = tid; i < kS * kM; i += 256) {
        int s = i >> 9, m = i & 511;
        Cs[s * kCsStride + m] = C0[(size_t)(b * kS + s) * kM + m];
    }
    for (int i = tid; i < kM; i += 256) vs[i] = v[i];
    if (tid < kS) empty_sh[tid] = empty0[b * kS + tid] ? 1.0f : 0.0f;
    if (tid < kSlots) slot_src[tid] = -1;
    if (tid < kN) flS[tid] = amb_flags[b * kN + tid];
    __syncthreads();

    const int sidx = tid >> 4;   // slot handled by this thread
    const int ml = tid & 15;     // lane within slot group

    for (int t = 0; t < kN; ++t) {
        if (!flS[t]) continue;

        const int pos = listPos[b * kN + t];
        const float* qp = qCache + (size_t)pos * kM;

        // e[s] = sum_m v[m] * tanh(q[m] + C[s][m]); float4, 16 lanes/slot
        const float* crow = &Cs[sidx * kCsStride];
        float acc = 0.f;
#pragma unroll
        for (int j = 0; j < 8; ++j) {
            int m = ml * 4 + j * 64;
            float4 q4 = *(const float4*)(qp + m);
            float4 c4 = *(const float4*)&crow[m];
            float4 v4 = *(const float4*)&vs[m];
            acc = fmaf(v4.x, tanh_fast(q4.x + c4.x), acc);
            acc = fmaf(v4.y, tanh_fast(q4.y + c4.y), acc);
            acc = fmaf(v4.z, tanh_fast(q4.z + c4.z), acc);
            acc = fmaf(v4.w, tanh_fast(q4.w + c4.w), acc);
        }
        acc += __shfl_xor(acc, 1); acc += __shfl_xor(acc, 2);
        acc += __shfl_xor(acc, 4); acc += __shfl_xor(acc, 8);
        if (ml == 0) e_sh[sidx] = acc;
        __syncthreads();

        // wave 0: softmax + empty mask + gumbel + argmax
        if (tid < 64) {
            int s = tid;
            float ev = (s < kS) ? e_sh[s] : -3.0e38f;
            float mx = ev;
            mx = fmaxf(mx, __shfl_xor(mx, 1));
            mx = fmaxf(mx, __shfl_xor(mx, 2));
            mx = fmaxf(mx, __shfl_xor(mx, 4));
            mx = fmaxf(mx, __shfl_xor(mx, 8));
            float w = (s < kS) ? __expf(ev - mx) : 0.f;
            float sm = w;
            sm += __shfl_xor(sm, 1); sm += __shfl_xor(sm, 2);
            sm += __shfl_xor(sm, 4); sm += __shfl_xor(sm, 8);
            w = w / sm;
            w += 10.0f * ((s < kS) ? empty_sh[s] : 0.f);
            float z;
            if (s < kS) {
                float u = gumbel_u[(size_t)(b * kN + t) * kS + s];
                u = fminf(fmaxf(u, 1e-20f), 1.0f);
                float g = -logf(-logf(u) + 1e-20f);
                z = w + g;            // tau = 1.0
            } else z = -3.0e38f;
            float zm = z;
            zm = fmaxf(zm, __shfl_xor(zm, 1));
            zm = fmaxf(zm, __shfl_xor(zm, 2));
            zm = fmaxf(zm, __shfl_xor(zm, 4));
            zm = fmaxf(zm, __shfl_xor(zm, 8));
            unsigned long long bal = __ballot(z == zm) & 0xFFFFull;
            if (s == 0) k_sh = __ffsll(bal) - 1;   // first-max (jnp.argmax)
        }
        __syncthreads();

        const int k = k_sh;
        if (tid < kS) out_log[(size_t)(b * kN + t) * kS + tid] = (tid == k) ? 1.f : 0.f;
        if (tid == 0) {
            float mv = states_mask[b * kN + t];
            wk_sh = (k < kSlots && mv != 0.0f) ? k : -1;
            nz_sh = 0;
        }
        __syncthreads();

        const int wk = wk_sh;
        if (wk >= 0) {
            float s0v = states[(size_t)(b * kN + t) * kM + tid];
            float s1v = states[(size_t)(b * kN + t) * kM + tid + 256];
            Xs[tid] = s0v; Xs[tid + 256] = s1v;
            if (s0v != 0.f || s1v != 0.f) nz_sh = 1;
            __syncthreads();
            // C[wk][r] = W[r][1024:1536] . state ; 16 lanes per row, coalesced
            const int g2 = tid >> 4, l2 = tid & 15;
            for (int r0 = 0; r0 < kM; r0 += 16) {
                int r = r0 + g2;
                const float* wr = W + (size_t)r * kW + 1024;
                float ca = 0.f;
#pragma unroll
                for (int k2 = l2 * 4; k2 < kM; k2 += 64) {
                    float4 w4 = *(const float4*)(wr + k2);
                    float4 x4 = *(const float4*)&Xs[k2];
                    ca = fmaf(w4.x, x4.x, ca); ca = fmaf(w4.y, x4.y, ca);
                    ca = fmaf(w4.z, x4.z, ca); ca = fmaf(w4.w, x4.w, ca);
                }
                ca += __shfl_xor(ca, 1); ca += __shfl_xor(ca, 2);
                ca += __shfl_xor(ca, 4); ca += __shfl_xor(ca, 8);
                if (l2 == 0) Cs[wk * kCsStride + r] = ca;
            }
            __syncthreads();
            if (tid == 0) {
                slot_src[wk] = t;
                empty_sh[wk] = nz_sh ? 0.f : 1.f;
            }
        }
        __syncthreads();
    }

    // epilogue: overwrite written slots only (bulk copy already done)
    for (int s = 0; s < kSlots; ++s) {
        int ts = slot_src[s];
        if (ts >= 0) {
            float* dst = out_hm + (size_t)(b * kSlots + s) * kM;
            dst[tid] = states[(size_t)(b * kN + ts) * kM + tid];
            dst[tid + 256] = states[(size_t)(b * kN + ts) * kM + tid + 256];
        }
    }
}

// ---------------------------------------------------------------------------
extern "C" void kernel_launch(void* const* d_in, const int* in_sizes, int n_in,
                              void* d_out, int out_size, void* d_ws, size_t ws_size,
                              hipStream_t stream)
{
    const float* his_mem      = (const float*)d_in[0];
    const float* states       = (const float*)d_in[1];
    const float* states_mask  = (const float*)d_in[2];
    const float* global_trace = (const float*)d_in[3];
    const float* null_mem     = (const float*)d_in[4];
    const float* gumbel_u     = (const float*)d_in[5];
    const float* attn_W       = (const float*)d_in[6];
    const float* attn_b       = (const float*)d_in[7];
    const float* v            = (const float*)d_in[8];

    // ws layout:
    //   C0      [4096*512]  f32   ( 8 MB)
    //   qCache  [32768*512] f32   (64 MB)
    //   empty0  [4096] i32 | cnt [256] i32 | total [16] i32
    //   ambBatch[256] i32  | listPos [32768] i32 | list [32768] u32
    //   amb     [32768] u8
    float* C0 = (float*)d_ws;
    float* qCache = C0 + (size_t)kB * kS * kM;
    int* empty0 = (int*)(qCache + (size_t)kB * kN * kM);
    int* cnt = empty0 + kB * kS;
    int* total = cnt + kB;
    int* ambBatch = total + 16;
    int* listPos = ambBatch + kB;
    unsigned* list = (unsigned*)(listPos + kB * kN);
    unsigned char* amb = (unsigned char*)(list + kB * kN);

    float* out_log = (float*)d_out + (size_t)kB * kSlots * kM;

    emptycopy_k<<<kB * kS / 4, 256, 0, stream>>>(his_mem, null_mem, (float*)d_out,
                                                 empty0, cnt, total);
    filter_k<<<kB * kN / 256, 256, 0, stream>>>(gumbel_u, empty0, out_log, amb,
                                                cnt, total, list, listPos, ambBatch);
    c0_k<<<dim3(64, kM / 64), 256, 0, stream>>>(attn_W, his_mem, null_mem, total,
                                                ambBatch, C0);
    q_k<<<256, 512, 0, stream>>>(total, list, states, global_trace, attn_W,
                                 attn_b, qCache);
    phaseB_k<<<kB, 256, 0, stream>>>(C0, empty0, amb, cnt, listPos, qCache,
                                     states, states_mask, gumbel_u, attn_W, v,
                                     (float*)d_out);
}

// Round 5
// 182.046 us; speedup vs baseline: 2.1766x; 1.5035x over previous
//
#include <hip/hip_runtime.h>

// Problem constants (fixed by setup_inputs)
constexpr int kB = 256;      // batch
constexpr int kN = 128;      // seq len
constexpr int kM = 512;      // mem width
constexpr int kSlots = 15;   // his_mem slots
constexpr int kS = 16;       // slots incl. null
constexpr int kW = 1536;     // attn_W row length (d_q + M)
constexpr int kCap = 8192;   // cached ambiguous-step capacity (n~66 measured)

__device__ __forceinline__ float tanh_fast(float x)
{
    float xc = fminf(15.f, fmaxf(-15.f, x));
    float ex = __expf(2.f * xc);
    return 1.f - 2.f * __builtin_amdgcn_rcpf(ex + 1.f);
}

// ---------------------------------------------------------------------------
// Empty-slot flags + zero counters + bulk hm copy (out_hm = his_mem).
// ---------------------------------------------------------------------------
__global__ __launch_bounds__(256) void emptycopy_k(
    const float* __restrict__ his_mem, const float* __restrict__ null_mem,
    float* __restrict__ out_hm, int* __restrict__ flags,
    int* __restrict__ cnt, int* __restrict__ total)
{
    if (blockIdx.x == 0) {
        cnt[threadIdx.x] = 0;                 // kB == 256 == blockDim
        if (threadIdx.x < 16) total[threadIdx.x] = 0;
    }
    int wave = threadIdx.x >> 6;
    int lane = threadIdx.x & 63;
    int row = blockIdx.x * 4 + wave;          // 0..4095
    int b = row >> 4, s = row & 15;
    const float* p = (s < kSlots) ? his_mem + (size_t)(b * kSlots + s) * kM
                                  : null_mem + (size_t)b * kM;
    float4 v0 = *(const float4*)(p + lane * 4);
    float4 v1 = *(const float4*)(p + 256 + lane * 4);
    int nz = (v0.x != 0.f) | (v0.y != 0.f) | (v0.z != 0.f) | (v0.w != 0.f) |
             (v1.x != 0.f) | (v1.y != 0.f) | (v1.z != 0.f) | (v1.w != 0.f);
    unsigned long long bal = __ballot(nz);
    if (lane == 0) flags[row] = (bal != 0ull) ? 0 : 1;
    if (s < kSlots) {
        float* dst = out_hm + (size_t)(b * kSlots + s) * kM;
        *(float4*)(dst + lane * 4) = v0;
        *(float4*)(dst + 256 + lane * 4) = v1;
    }
}

// ---------------------------------------------------------------------------
// Filter: flag (b,t) where argmax could differ from null slot 15, write the
// default one-hot(15) log rows, append to compact step list + batch list.
// ---------------------------------------------------------------------------
__global__ __launch_bounds__(256) void filter_k(
    const float* __restrict__ gumbel_u, const int* __restrict__ empty0,
    float* __restrict__ out_log, unsigned char* __restrict__ amb_flags,
    int* __restrict__ cnt, int* __restrict__ total, unsigned* __restrict__ list,
    int* __restrict__ listPos, int* __restrict__ ambBatch)
{
    int idx = blockIdx.x * 256 + threadIdx.x;    // b*128 + t
    int b = idx >> 7;
    const float* up = gumbel_u + (size_t)idx * kS;
    float g[kS];
#pragma unroll
    for (int s = 0; s < kS; ++s) {
        float u = up[s];
        u = fminf(fmaxf(u, 1e-20f), 1.0f);
        g[s] = -logf(-logf(u) + 1e-20f);
    }
    float e15 = empty0[b * kS + 15] ? 1.f : 0.f;
    float rhs = g[15] + 10.f * e15 - 1.01f;      // ambiguous iff g_k+10*ek >= rhs
    bool amb = false;
#pragma unroll
    for (int s = 0; s < kSlots; ++s) {
        float ek = empty0[b * kS + s] ? 1.f : 0.f;
        amb = amb || (g[s] + 10.f * ek >= rhs);
    }
    amb_flags[idx] = amb ? 1 : 0;
    if (amb) {
        int pos = atomicAdd(&total[0], 1);
        if (pos < kCap) list[pos] = (unsigned)idx;
        listPos[idx] = pos;
        int prev = atomicAdd(&cnt[b], 1);
        if (prev == 0) {
            int bp = atomicAdd(&total[1], 1);
            ambBatch[bp] = b;
        }
    }
    float* lp = out_log + (size_t)idx * kS;
    float4 zz = make_float4(0.f, 0.f, 0.f, 0.f);
    *(float4*)(lp + 0) = zz;
    *(float4*)(lp + 4) = zz;
    *(float4*)(lp + 8) = zz;
    *(float4*)(lp + 12) = make_float4(0.f, 0.f, 0.f, 1.f);
}

// ---------------------------------------------------------------------------
// C0[b*16+s][m] = W[m][1024:1536] . mem[b,s] — gathered over the compacted
// ambiguous-batch list (4 batches = 64 rows per block.x).
// ---------------------------------------------------------------------------
__global__ __launch_bounds__(256) void c0_k(
    const float* __restrict__ W, const float* __restrict__ his_mem,
    const float* __restrict__ null_mem, const int* __restrict__ total,
    const int* __restrict__ ambBatch, float* __restrict__ C0)
{
    const int nab = total[1];
    if ((int)blockIdx.x * 4 >= nab) return;
    __shared__ float As[16 * 68];
    __shared__ float Bs[16 * 68];
    const int n0 = blockIdx.y * 64;
    const int tid = threadIdx.x;
    const int row_l = tid >> 2;
    const int k4 = (tid & 3) * 4;
    const int ty = tid >> 4, tx = tid & 15;

    int bi = blockIdx.x * 4 + (row_l >> 4);
    if (bi >= nab) bi = nab - 1;               // clamp: redundant same-value work
    const int b = ambBatch[bi];
    const int s = row_l & 15;
    const float* ap = (s < kSlots) ? (his_mem + (size_t)(b * kSlots + s) * kM)
                                   : (null_mem + (size_t)b * kM);
    const float* wp = W + (size_t)(n0 + row_l) * kW + 1024;

    float acc[4][4];
#pragma unroll
    for (int i = 0; i < 4; ++i)
#pragma unroll
        for (int j = 0; j < 4; ++j) acc[i][j] = 0.f;

    for (int kt = 0; kt < kM; kt += 16) {
        float4 a4 = *(const float4*)(ap + kt + k4);
        float4 b4 = *(const float4*)(wp + kt + k4);
        __syncthreads();
        As[(k4 + 0) * 68 + row_l] = a4.x; As[(k4 + 1) * 68 + row_l] = a4.y;
        As[(k4 + 2) * 68 + row_l] = a4.z; As[(k4 + 3) * 68 + row_l] = a4.w;
        Bs[(k4 + 0) * 68 + row_l] = b4.x; Bs[(k4 + 1) * 68 + row_l] = b4.y;
        Bs[(k4 + 2) * 68 + row_l] = b4.z; Bs[(k4 + 3) * 68 + row_l] = b4.w;
        __syncthreads();
#pragma unroll
        for (int k = 0; k < 16; ++k) {
            const float4 av = *(const float4*)&As[k * 68 + ty * 4];
            const float4 bv = *(const float4*)&Bs[k * 68 + tx * 4];
            acc[0][0] = fmaf(av.x, bv.x, acc[0][0]);
            acc[0][1] = fmaf(av.x, bv.y, acc[0][1]);
            acc[0][2] = fmaf(av.x, bv.z, acc[0][2]);
            acc[0][3] = fmaf(av.x, bv.w, acc[0][3]);
            acc[1][0] = fmaf(av.y, bv.x, acc[1][0]);
            acc[1][1] = fmaf(av.y, bv.y, acc[1][1]);
            acc[1][2] = fmaf(av.y, bv.z, acc[1][2]);
            acc[1][3] = fmaf(av.y, bv.w, acc[1][3]);
            acc[2][0] = fmaf(av.z, bv.x, acc[2][0]);
            acc[2][1] = fmaf(av.z, bv.y, acc[2][1]);
            acc[2][2] = fmaf(av.z, bv.z, acc[2][2]);
            acc[2][3] = fmaf(av.z, bv.w, acc[2][3]);
            acc[3][0] = fmaf(av.w, bv.x, acc[3][0]);
            acc[3][1] = fmaf(av.w, bv.y, acc[3][1]);
            acc[3][2] = fmaf(av.w, bv.z, acc[3][2]);
            acc[3][3] = fmaf(av.w, bv.w, acc[3][3]);
        }
    }
#pragma unroll
    for (int i = 0; i < 4; ++i) {
        int rl = ty * 4 + i;
        int bij = blockIdx.x * 4 + (rl >> 4);
        if (bij >= nab) bij = nab - 1;
        int ro = ambBatch[bij] * kS + (rl & 15);
        float4 o = make_float4(acc[i][0], acc[i][1], acc[i][2], acc[i][3]);
        *(float4*)(C0 + (size_t)ro * kM + n0 + tx * 4) = o;
    }
}

// ---------------------------------------------------------------------------
// qcw_k: for every cached ambiguous step i, compute BOTH
//   q[r]  = bias[r] + W[r][0:1024] . [state|gt]
//   cw[r] = W[r][1024:1536] . state          (the C-row if this step writes)
// Work unit = (step, 32-row chunk): n*16 chunks spread over 2048 blocks, so
// per-block serial traffic is ~192 KB (vs 2 MB in round 4's q_k).
// Also records stepNz[i] = any(state != 0).
// ---------------------------------------------------------------------------
__global__ __launch_bounds__(256) void qcw_k(
    const int* __restrict__ total, const unsigned* __restrict__ list,
    const float* __restrict__ states, const float* __restrict__ global_trace,
    const float* __restrict__ W, const float* __restrict__ attn_b,
    float* __restrict__ qCache, float* __restrict__ cwCache,
    int* __restrict__ stepNz)
{
    int n = total[0];
    if (n > kCap) n = kCap;
    const int tid = threadIdx.x;
    __shared__ float Xs[1024];
    __shared__ int nzs;

    for (int c = blockIdx.x; c < n * 16; c += gridDim.x) {
        const int i = c >> 4;        // step index in list
        const int j = c & 15;        // 32-row chunk
        const int idx = (int)list[i];
        const int b = idx >> 7;
        __syncthreads();             // protect Xs reuse across iterations
        if (tid == 0) nzs = 0;
        __syncthreads();
        float s0 = states[(size_t)idx * kM + tid];
        float s1 = states[(size_t)idx * kM + 256 + tid];
        Xs[tid] = s0; Xs[256 + tid] = s1;
        Xs[512 + tid] = global_trace[(size_t)b * kM + tid];
        Xs[768 + tid] = global_trace[(size_t)b * kM + 256 + tid];
        if (s0 != 0.f || s1 != 0.f) nzs = 1;
        __syncthreads();

        const int g = tid >> 4;      // 0..15 row group
        const int l = tid & 15;      // lane in group
#pragma unroll
        for (int p = 0; p < 2; ++p) {
            const int r = j * 32 + p * 16 + g;
            const float* wr = W + (size_t)r * kW;
            float accq = 0.f, accc = 0.f;
#pragma unroll
            for (int jj = 0; jj < 16; ++jj) {
                int k = l * 4 + jj * 64;
                float4 w4 = *(const float4*)(wr + k);
                float4 x4 = *(const float4*)&Xs[k];
                accq = fmaf(w4.x, x4.x, accq); accq = fmaf(w4.y, x4.y, accq);
                accq = fmaf(w4.z, x4.z, accq); accq = fmaf(w4.w, x4.w, accq);
            }
#pragma unroll
            for (int jj = 0; jj < 8; ++jj) {
                int k = l * 4 + jj * 64;
                float4 w4 = *(const float4*)(wr + 1024 + k);
                float4 x4 = *(const float4*)&Xs[k];
                accc = fmaf(w4.x, x4.x, accc); accc = fmaf(w4.y, x4.y, accc);
                accc = fmaf(w4.z, x4.z, accc); accc = fmaf(w4.w, x4.w, accc);
            }
            accq += __shfl_xor(accq, 1); accq += __shfl_xor(accq, 2);
            accq += __shfl_xor(accq, 4); accq += __shfl_xor(accq, 8);
            accc += __shfl_xor(accc, 1); accc += __shfl_xor(accc, 2);
            accc += __shfl_xor(accc, 4); accc += __shfl_xor(accc, 8);
            if (l == 0) {
                qCache[(size_t)i * kM + r] = accq + attn_b[r];
                cwCache[(size_t)i * kM + r] = accc;
            }
        }
        if (tid == 0 && j == 0) stepNz[i] = nzs;
    }
}

// ---------------------------------------------------------------------------
// Phase B: per ambiguous batch, walk flagged steps in order. Serial chain is
// now W-free: e-eval from qCache + LDS C; writes copy cwCache into LDS.
// (Inline recompute fallback only if listPos >= kCap — never with real input.)
// ---------------------------------------------------------------------------
constexpr int kCsStride = 528;   // 512+16 -> at most 2-way bank aliasing (free)

__global__ __launch_bounds__(256) void phaseB_k(
    const float* __restrict__ C0, const int* __restrict__ empty0,
    const unsigned char* __restrict__ amb_flags, const int* __restrict__ cnt,
    const int* __restrict__ listPos, const float* __restrict__ qCache,
    const float* __restrict__ cwCache, const int* __restrict__ stepNz,
    const float* __restrict__ states, const float* __restrict__ states_mask,
    const float* __restrict__ gumbel_u, const float* __restrict__ global_trace,
    const float* __restrict__ W, const float* __restrict__ attn_b,
    const float* __restrict__ v, float* __restrict__ out)
{
    const int b = blockIdx.x;
    if (cnt[b] == 0) return;     // defaults already correct
    const int tid = threadIdx.x;
    float* out_hm = out;
    float* out_log = out + (size_t)kB * kSlots * kM;

    __shared__ float Cs[kS * kCsStride];
    __shared__ float Xb[1024];          // [state | gt] — fallback path only
    __shared__ float Qb[kM];            // fallback q
    __shared__ float vs[kM];
    __shared__ float e_sh[kS];
    __shared__ float empty_sh[kS];
    __shared__ unsigned char flS[kN];
    __shared__ int slot_src[kSlots];
    __shared__ int k_sh, wk_sh, nz_sh;

    for (int i = tid; i < kS * kM; i += 256) {
        int s = i >> 9, m = i & 511;
        Cs[s * kCsStride + m] = C0[(size_t)(b * kS + s) * kM + m];
    }
    for (int i = tid; i < kM; i += 256) {
        vs[i] = v[i];
        Xb[512 + i] = global_trace[(size_t)b * kM + i];
    }
    if (tid < kS) empty_sh[tid] = empty0[b * kS + tid] ? 1.0f : 0.0f;
    if (tid < kSlots) slot_src[tid] = -1;
    if (tid < kN) flS[tid] = amb_flags[b * kN + tid];
    __syncthreads();

    const int sidx = tid >> 4;   // slot handled by this thread
    const int ml = tid & 15;     // lane within slot group

    for (int t = 0; t < kN; ++t) {
        if (!flS[t]) continue;

        const int pos = listPos[b * kN + t];
        const float* qp;
        if (pos < kCap) {
            qp = qCache + (size_t)pos * kM;
        } else {
            // fallback: recompute q inline (dead code for real inputs)
            Xb[tid] = states[(size_t)(b * kN + t) * kM + tid];
            Xb[256 + tid] = states[(size_t)(b * kN + t) * kM + 256 + tid];
            __syncthreads();
            const int g2 = tid >> 4, l2 = tid & 15;
            for (int r0 = 0; r0 < kM; r0 += 16) {
                int r = r0 + g2;
                const float* wr = W + (size_t)r * kW;
                float a = 0.f;
                for (int k = l2 * 4; k < 1024; k += 64) {
                    float4 w4 = *(const float4*)(wr + k);
                    float4 x4 = *(const float4*)&Xb[k];
                    a = fmaf(w4.x, x4.x, a); a = fmaf(w4.y, x4.y, a);
                    a = fmaf(w4.z, x4.z, a); a = fmaf(w4.w, x4.w, a);
                }
                a += __shfl_xor(a, 1); a += __shfl_xor(a, 2);
                a += __shfl_xor(a, 4); a += __shfl_xor(a, 8);
                if (l2 == 0) Qb[r] = a + attn_b[r];
            }
            __syncthreads();
            qp = Qb;
        }

        // e[s] = sum_m v[m] * tanh(q[m] + C[s][m]); float4, 16 lanes/slot
        const float* crow = &Cs[sidx * kCsStride];
        float acc = 0.f;
#pragma unroll
        for (int j = 0; j < 8; ++j) {
            int m = ml * 4 + j * 64;
            float4 q4 = *(const float4*)(qp + m);
            float4 c4 = *(const float4*)&crow[m];
            float4 v4 = *(const float4*)&vs[m];
            acc = fmaf(v4.x, tanh_fast(q4.x + c4.x), acc);
            acc = fmaf(v4.y, tanh_fast(q4.y + c4.y), acc);
            acc = fmaf(v4.z, tanh_fast(q4.z + c4.z), acc);
            acc = fmaf(v4.w, tanh_fast(q4.w + c4.w), acc);
        }
        acc += __shfl_xor(acc, 1); acc += __shfl_xor(acc, 2);
        acc += __shfl_xor(acc, 4); acc += __shfl_xor(acc, 8);
        if (ml == 0) e_sh[sidx] = acc;
        __syncthreads();

        // wave 0: softmax + empty mask + gumbel + argmax
        if (tid < 64) {
            int s = tid;
            float ev = (s < kS) ? e_sh[s] : -3.0e38f;
            float mx = ev;
            mx = fmaxf(mx, __shfl_xor(mx, 1));
            mx = fmaxf(mx, __shfl_xor(mx, 2));
            mx = fmaxf(mx, __shfl_xor(mx, 4));
            mx = fmaxf(mx, __shfl_xor(mx, 8));
            float w = (s < kS) ? __expf(ev - mx) : 0.f;
            float sm = w;
            sm += __shfl_xor(sm, 1); sm += __shfl_xor(sm, 2);
            sm += __shfl_xor(sm, 4); sm += __shfl_xor(sm, 8);
            w = w / sm;
            w += 10.0f * ((s < kS) ? empty_sh[s] : 0.f);
            float z;
            if (s < kS) {
                float u = gumbel_u[(size_t)(b * kN + t) * kS + s];
                u = fminf(fmaxf(u, 1e-20f), 1.0f);
                float g = -logf(-logf(u) + 1e-20f);
                z = w + g;            // tau = 1.0
            } else z = -3.0e38f;
            float zm = z;
            zm = fmaxf(zm, __shfl_xor(zm, 1));
            zm = fmaxf(zm, __shfl_xor(zm, 2));
            zm = fmaxf(zm, __shfl_xor(zm, 4));
            zm = fmaxf(zm, __shfl_xor(zm, 8));
            unsigned long long bal = __ballot(z == zm) & 0xFFFFull;
            if (s == 0) k_sh = __ffsll(bal) - 1;   // first-max (jnp.argmax)
        }
        __syncthreads();

        const int k = k_sh;
        if (tid < kS) out_log[(size_t)(b * kN + t) * kS + tid] = (tid == k) ? 1.f : 0.f;
        if (tid == 0) {
            float mv = states_mask[b * kN + t];
            wk_sh = (k < kSlots && mv != 0.0f) ? k : -1;
            nz_sh = 0;
        }
        __syncthreads();

        const int wk = wk_sh;
        if (wk >= 0) {
            if (pos < kCap) {
                // cached: C-row copy + precomputed nz flag
                Cs[wk * kCsStride + tid] = cwCache[(size_t)pos * kM + tid];
                Cs[wk * kCsStride + 256 + tid] = cwCache[(size_t)pos * kM + 256 + tid];
                if (tid == 0) {
                    slot_src[wk] = t;
                    empty_sh[wk] = stepNz[pos] ? 0.f : 1.f;
                }
            } else {
                // fallback: inline cw GEMV from staged Xb (dead code normally)
                if (Xb[tid] != 0.f || Xb[256 + tid] != 0.f) nz_sh = 1;
                __syncthreads();
                const int g2 = tid >> 4, l2 = tid & 15;
                for (int r0 = 0; r0 < kM; r0 += 16) {
                    int r = r0 + g2;
                    const float* wr = W + (size_t)r * kW + 1024;
                    float ca = 0.f;
                    for (int k2 = l2 * 4; k2 < kM; k2 += 64) {
                        float4 w4 = *(const float4*)(wr + k2);
                        float4 x4 = *(const float4*)&Xb[k2];
                        ca = fmaf(w4.x, x4.x, ca); ca = fmaf(w4.y, x4.y, ca);
                        ca = fmaf(w4.z, x4.z, ca); ca = fmaf(w4.w, x4.w, ca);
                    }
                    ca += __shfl_xor(ca, 1); ca += __shfl_xor(ca, 2);
                    ca += __shfl_xor(ca, 4); ca += __shfl_xor(ca, 8);
                    if (l2 == 0) Cs[wk * kCsStride + r] = ca;
                }
                __syncthreads();
                if (tid == 0) {
                    slot_src[wk] = t;
                    empty_sh[wk] = nz_sh ? 0.f : 1.f;
                }
            }
        }
        __syncthreads();
    }

    // epilogue: overwrite written slots only (bulk copy already done)
    for (int s = 0; s < kSlots; ++s) {
        int ts = slot_src[s];
        if (ts >= 0) {
            float* dst = out_hm + (size_t)(b * kSlots + s) * kM;
            dst[tid] = states[(size_t)(b * kN + ts) * kM + tid];
            dst[tid + 256] = states[(size_t)(b * kN + ts) * kM + tid + 256];
        }
    }
}

// ---------------------------------------------------------------------------
extern "C" void kernel_launch(void* const* d_in, const int* in_sizes, int n_in,
                              void* d_out, int out_size, void* d_ws, size_t ws_size,
                              hipStream_t stream)
{
    const float* his_mem      = (const float*)d_in[0];
    const float* states       = (const float*)d_in[1];
    const float* states_mask  = (const float*)d_in[2];
    const float* global_trace = (const float*)d_in[3];
    const float* null_mem     = (const float*)d_in[4];
    const float* gumbel_u     = (const float*)d_in[5];
    const float* attn_W       = (const float*)d_in[6];
    const float* attn_b       = (const float*)d_in[7];
    const float* v            = (const float*)d_in[8];

    // ws layout (~40.6 MB):
    //   C0      [4096*512] f32   ( 8 MB)
    //   qCache  [8192*512] f32   (16 MB)
    //   cwCache [8192*512] f32   (16 MB)
    //   empty0[4096] i32 | cnt[256] i32 | total[16] i32 | ambBatch[256] i32
    //   stepNz[8192] i32 | listPos[32768] i32 | list[32768] u32 | amb[32768] u8
    float* C0 = (float*)d_ws;
    float* qCache = C0 + (size_t)kB * kS * kM;
    float* cwCache = qCache + (size_t)kCap * kM;
    int* empty0 = (int*)(cwCache + (size_t)kCap * kM);
    int* cnt = empty0 + kB * kS;
    int* total = cnt + kB;
    int* ambBatch = total + 16;
    int* stepNz = ambBatch + kB;
    int* listPos = stepNz + kCap;
    unsigned* list = (unsigned*)(listPos + kB * kN);
    unsigned char* amb = (unsigned char*)(list + kB * kN);

    float* out_log = (float*)d_out + (size_t)kB * kSlots * kM;

    emptycopy_k<<<kB * kS / 4, 256, 0, stream>>>(his_mem, null_mem, (float*)d_out,
                                                 empty0, cnt, total);
    filter_k<<<kB * kN / 256, 256, 0, stream>>>(gumbel_u, empty0, out_log, amb,
                                                cnt, total, list, listPos, ambBatch);
    c0_k<<<dim3(64, kM / 64), 256, 0, stream>>>(attn_W, his_mem, null_mem, total,
                                                ambBatch, C0);
    qcw_k<<<2048, 256, 0, stream>>>(total, list, states, global_trace, attn_W,
                                    attn_b, qCache, cwCache, stepNz);
    phaseB_k<<<kB, 256, 0, stream>>>(C0, empty0, amb, cnt, listPos, qCache,
                                     cwCache, stepNz, states, states_mask,
                                     gumbel_u, global_trace, attn_W, attn_b, v,
                                     (float*)d_out);
}

// Round 6
// 169.355 us; speedup vs baseline: 2.3397x; 1.0749x over previous
//
#include <hip/hip_runtime.h>

// Problem constants (fixed by setup_inputs)
constexpr int kB = 256;      // batch
constexpr int kN = 128;      // seq len
constexpr int kM = 512;      // mem width
constexpr int kSlots = 15;   // his_mem slots
constexpr int kS = 16;       // slots incl. null
constexpr int kW = 1536;     // attn_W row length (d_q + M)
constexpr int kCap = 8192;   // cached ambiguous-step capacity (n~66 measured)

__device__ __forceinline__ float tanh_fast(float x)
{
    float xc = fminf(15.f, fmaxf(-15.f, x));
    float ex = __expf(2.f * xc);
    return 1.f - 2.f * __builtin_amdgcn_rcpf(ex + 1.f);
}

// ---------------------------------------------------------------------------
// prep1: one block per batch. Fuses: empty-slot flags, bulk hm copy
// (out_hm = his_mem), gumbel ambiguity filter, default one-hot(15) log rows,
// and compact list building. cnt/total zeroed by a preceding hipMemsetAsync.
// ---------------------------------------------------------------------------
__global__ __launch_bounds__(256) void prep1_k(
    const float* __restrict__ his_mem, const float* __restrict__ null_mem,
    const float* __restrict__ gumbel_u, float* __restrict__ out,
    int* __restrict__ empty0, int* __restrict__ cnt, int* __restrict__ total,
    unsigned* __restrict__ list, int* __restrict__ listPos,
    int* __restrict__ ambBatch, unsigned char* __restrict__ amb_flags)
{
    const int b = blockIdx.x;
    const int tid = threadIdx.x;
    const int wave = tid >> 6, lane = tid & 63;
    __shared__ int eflag[kS];
    float* out_hm = out;
    float* out_log = out + (size_t)kB * kSlots * kM;

    // empty flags + hm copy: each of 4 waves handles 4 slot-rows
    for (int s = wave; s < kS; s += 4) {
        const float* p = (s < kSlots) ? his_mem + (size_t)(b * kSlots + s) * kM
                                      : null_mem + (size_t)b * kM;
        float4 v0 = *(const float4*)(p + lane * 4);
        float4 v1 = *(const float4*)(p + 256 + lane * 4);
        int nz = (v0.x != 0.f) | (v0.y != 0.f) | (v0.z != 0.f) | (v0.w != 0.f) |
                 (v1.x != 0.f) | (v1.y != 0.f) | (v1.z != 0.f) | (v1.w != 0.f);
        unsigned long long bal = __ballot(nz);
        if (lane == 0) eflag[s] = (bal == 0ull) ? 1 : 0;
        if (s < kSlots) {
            float* dst = out_hm + (size_t)(b * kSlots + s) * kM;
            *(float4*)(dst + lane * 4) = v0;
            *(float4*)(dst + 256 + lane * 4) = v1;
        }
    }
    __syncthreads();
    if (tid < kS) empty0[b * kS + tid] = eflag[tid];

    // filter: threads 0..127 each own step t = tid
    if (tid < kN) {
        const int idx = b * kN + tid;
        const float* up = gumbel_u + (size_t)idx * kS;
        float g[kS];
#pragma unroll
        for (int s = 0; s < kS; ++s) {
            float u = fminf(fmaxf(up[s], 1e-20f), 1.0f);
            g[s] = -logf(-logf(u) + 1e-20f);
        }
        float rhs = g[15] + 10.f * (eflag[15] ? 1.f : 0.f) - 1.01f;
        bool amb = false;
#pragma unroll
        for (int s = 0; s < kSlots; ++s)
            amb = amb || (g[s] + 10.f * (eflag[s] ? 1.f : 0.f) >= rhs);
        amb_flags[idx] = amb ? 1 : 0;
        if (amb) {
            int pos = atomicAdd(&total[0], 1);
            if (pos < kCap) list[pos] = (unsigned)idx;
            listPos[idx] = pos;
            int prev = atomicAdd(&cnt[b], 1);
            if (prev == 0) {
                int bp = atomicAdd(&total[1], 1);
                ambBatch[bp] = b;
            }
        }
        float* lp = out_log + (size_t)idx * kS;
        float4 zz = make_float4(0.f, 0.f, 0.f, 0.f);
        *(float4*)(lp + 0) = zz;
        *(float4*)(lp + 4) = zz;
        *(float4*)(lp + 8) = zz;
        *(float4*)(lp + 12) = make_float4(0.f, 0.f, 0.f, 1.f);
    }
}

// ---------------------------------------------------------------------------
// prep2: fused c0-GEMM (blocks 0..511) + qcw GEMV chunks (blocks 512..2559).
// The two halves are independent; fusing lets them overlap on one stream.
//
// c0 path: C0[b*16+s][m] = W[m][1024:1536] . mem[b,s], gathered over the
//   compacted ambiguous-batch list (4 batches = 64 rows per x-tile).
// qcw path: per cached ambiguous step i and 32-row chunk j:
//   q[r]  = bias[r] + W[r][0:1024] . [state|gt]
//   cw[r] = W[r][1024:1536] . state      (C-row if this step writes)
//   stepNz[i] = any(state != 0)
// ---------------------------------------------------------------------------
__global__ __launch_bounds__(256) void prep2_k(
    const float* __restrict__ W, const float* __restrict__ his_mem,
    const float* __restrict__ null_mem, const float* __restrict__ states,
    const float* __restrict__ global_trace, const float* __restrict__ attn_b,
    const int* __restrict__ total, const int* __restrict__ ambBatch,
    const unsigned* __restrict__ list, float* __restrict__ C0,
    float* __restrict__ qCache, float* __restrict__ cwCache,
    int* __restrict__ stepNz)
{
    const int tid = threadIdx.x;

    if (blockIdx.x < 512) {
        // ------------------------- c0 GEMM path ---------------------------
        const int nab = total[1];
        const int cx = blockIdx.x >> 3;          // 0..63  (row tiles)
        const int cy = blockIdx.x & 7;           // 0..7   (col tiles)
        if (cx * 4 >= nab) return;
        __shared__ float As[16 * 68];
        __shared__ float Bs[16 * 68];
        const int n0 = cy * 64;
        const int row_l = tid >> 2;
        const int k4 = (tid & 3) * 4;
        const int ty = tid >> 4, tx = tid & 15;

        int bi = cx * 4 + (row_l >> 4);
        if (bi >= nab) bi = nab - 1;             // clamp: redundant work only
        const int b = ambBatch[bi];
        const int s = row_l & 15;
        const float* ap = (s < kSlots) ? (his_mem + (size_t)(b * kSlots + s) * kM)
                                       : (null_mem + (size_t)b * kM);
        const float* wp = W + (size_t)(n0 + row_l) * kW + 1024;

        float acc[4][4];
#pragma unroll
        for (int i = 0; i < 4; ++i)
#pragma unroll
            for (int j = 0; j < 4; ++j) acc[i][j] = 0.f;

        for (int kt = 0; kt < kM; kt += 16) {
            float4 a4 = *(const float4*)(ap + kt + k4);
            float4 b4 = *(const float4*)(wp + kt + k4);
            __syncthreads();
            As[(k4 + 0) * 68 + row_l] = a4.x; As[(k4 + 1) * 68 + row_l] = a4.y;
            As[(k4 + 2) * 68 + row_l] = a4.z; As[(k4 + 3) * 68 + row_l] = a4.w;
            Bs[(k4 + 0) * 68 + row_l] = b4.x; Bs[(k4 + 1) * 68 + row_l] = b4.y;
            Bs[(k4 + 2) * 68 + row_l] = b4.z; Bs[(k4 + 3) * 68 + row_l] = b4.w;
            __syncthreads();
#pragma unroll
            for (int k = 0; k < 16; ++k) {
                const float4 av = *(const float4*)&As[k * 68 + ty * 4];
                const float4 bv = *(const float4*)&Bs[k * 68 + tx * 4];
                acc[0][0] = fmaf(av.x, bv.x, acc[0][0]);
                acc[0][1] = fmaf(av.x, bv.y, acc[0][1]);
                acc[0][2] = fmaf(av.x, bv.z, acc[0][2]);
                acc[0][3] = fmaf(av.x, bv.w, acc[0][3]);
                acc[1][0] = fmaf(av.y, bv.x, acc[1][0]);
                acc[1][1] = fmaf(av.y, bv.y, acc[1][1]);
                acc[1][2] = fmaf(av.y, bv.z, acc[1][2]);
                acc[1][3] = fmaf(av.y, bv.w, acc[1][3]);
                acc[2][0] = fmaf(av.z, bv.x, acc[2][0]);
                acc[2][1] = fmaf(av.z, bv.y, acc[2][1]);
                acc[2][2] = fmaf(av.z, bv.z, acc[2][2]);
                acc[2][3] = fmaf(av.z, bv.w, acc[2][3]);
                acc[3][0] = fmaf(av.w, bv.x, acc[3][0]);
                acc[3][1] = fmaf(av.w, bv.y, acc[3][1]);
                acc[3][2] = fmaf(av.w, bv.z, acc[3][2]);
                acc[3][3] = fmaf(av.w, bv.w, acc[3][3]);
            }
        }
#pragma unroll
        for (int i = 0; i < 4; ++i) {
            int rl = ty * 4 + i;
            int bij = cx * 4 + (rl >> 4);
            if (bij >= nab) bij = nab - 1;
            int ro = ambBatch[bij] * kS + (rl & 15);
            float4 o = make_float4(acc[i][0], acc[i][1], acc[i][2], acc[i][3]);
            *(float4*)(C0 + (size_t)ro * kM + n0 + tx * 4) = o;
        }
    } else {
        // ------------------------- qcw GEMV path --------------------------
        int n = total[0];
        if (n > kCap) n = kCap;
        __shared__ float Xs[1024];
        __shared__ int nzs;

        for (int c = (int)blockIdx.x - 512; c < n * 16; c += 2048) {
            const int i = c >> 4;        // step index in list
            const int j = c & 15;        // 32-row chunk
            const int idx = (int)list[i];
            const int b = idx >> 7;
            __syncthreads();             // protect Xs reuse across iterations
            if (tid == 0) nzs = 0;
            __syncthreads();
            float s0 = states[(size_t)idx * kM + tid];
            float s1 = states[(size_t)idx * kM + 256 + tid];
            Xs[tid] = s0; Xs[256 + tid] = s1;
            Xs[512 + tid] = global_trace[(size_t)b * kM + tid];
            Xs[768 + tid] = global_trace[(size_t)b * kM + 256 + tid];
            if (s0 != 0.f || s1 != 0.f) nzs = 1;
            __syncthreads();

            const int g = tid >> 4;      // 0..15 row group
            const int l = tid & 15;      // lane in group
#pragma unroll
            for (int p = 0; p < 2; ++p) {
                const int r = j * 32 + p * 16 + g;
                const float* wr = W + (size_t)r * kW;
                float accq = 0.f, accc = 0.f;
#pragma unroll
                for (int jj = 0; jj < 16; ++jj) {
                    int k = l * 4 + jj * 64;
                    float4 w4 = *(const float4*)(wr + k);
                    float4 x4 = *(const float4*)&Xs[k];
                    accq = fmaf(w4.x, x4.x, accq); accq = fmaf(w4.y, x4.y, accq);
                    accq = fmaf(w4.z, x4.z, accq); accq = fmaf(w4.w, x4.w, accq);
                }
#pragma unroll
                for (int jj = 0; jj < 8; ++jj) {
                    int k = l * 4 + jj * 64;
                    float4 w4 = *(const float4*)(wr + 1024 + k);
                    float4 x4 = *(const float4*)&Xs[k];
                    accc = fmaf(w4.x, x4.x, accc); accc = fmaf(w4.y, x4.y, accc);
                    accc = fmaf(w4.z, x4.z, accc); accc = fmaf(w4.w, x4.w, accc);
                }
                accq += __shfl_xor(accq, 1); accq += __shfl_xor(accq, 2);
                accq += __shfl_xor(accq, 4); accq += __shfl_xor(accq, 8);
                accc += __shfl_xor(accc, 1); accc += __shfl_xor(accc, 2);
                accc += __shfl_xor(accc, 4); accc += __shfl_xor(accc, 8);
                if (l == 0) {
                    qCache[(size_t)i * kM + r] = accq + attn_b[r];
                    cwCache[(size_t)i * kM + r] = accc;
                }
            }
            if (tid == 0 && j == 0) stepNz[i] = nzs;
        }
    }
}

// ---------------------------------------------------------------------------
// Phase B: per ambiguous batch, walk flagged steps in order. Serial chain is
// W-free: e-eval from qCache + LDS C; writes copy cwCache into LDS.
// (Inline recompute fallback only if listPos >= kCap — never with real input.)
// ---------------------------------------------------------------------------
constexpr int kCsStride = 528;   // 512+16 -> at most 2-way bank aliasing (free)

__global__ __launch_bounds__(256) void phaseB_k(
    const float* __restrict__ C0, const int* __restrict__ empty0,
    const unsigned char* __restrict__ amb_flags, const int* __restrict__ cnt,
    const int* __restrict__ listPos, const float* __restrict__ qCache,
    const float* __restrict__ cwCache, const int* __restrict__ stepNz,
    const float* __restrict__ states, const float* __restrict__ states_mask,
    const float* __restrict__ gumbel_u, const float* __restrict__ global_trace,
    const float* __restrict__ W, const float* __restrict__ attn_b,
    const float* __restrict__ v, float* __restrict__ out)
{
    const int b = blockIdx.x;
    if (cnt[b] == 0) return;     // defaults already correct
    const int tid = threadIdx.x;
    float* out_hm = out;
    float* out_log = out + (size_t)kB * kSlots * kM;

    __shared__ float Cs[kS * kCsStride];
    __shared__ float Xb[1024];          // [state | gt] — fallback path only
    __shared__ float Qb[kM];            // fallback q
    __shared__ float vs[kM];
    __shared__ float e_sh[kS];
    __shared__ float empty_sh[kS];
    __shared__ unsigned char flS[kN];
    __shared__ int slot_src[kSlots];
    __shared__ int k_sh, wk_sh, nz_sh;

    for (int i = tid; i < kS * kM; i += 256) {
        int s = i >> 9, m = i & 511;
        Cs[s * kCsStride + m] = C0[(size_t)(b * kS + s) * kM + m];
    }
    for (int i = tid; i < kM; i += 256) {
        vs[i] = v[i];
        Xb[512 + i] = global_trace[(size_t)b * kM + i];
    }
    if (tid < kS) empty_sh[tid] = empty0[b * kS + tid] ? 1.0f : 0.0f;
    if (tid < kSlots) slot_src[tid] = -1;
    if (tid < kN) flS[tid] = amb_flags[b * kN + tid];
    __syncthreads();

    const int sidx = tid >> 4;   // slot handled by this thread
    const int ml = tid & 15;     // lane within slot group

    for (int t = 0; t < kN; ++t) {
        if (!flS[t]) continue;

        const int pos = listPos[b * kN + t];
        const float* qp;
        if (pos < kCap) {
            qp = qCache + (size_t)pos * kM;
        } else {
            // fallback: recompute q inline (dead code for real inputs)
            Xb[tid] = states[(size_t)(b * kN + t) * kM + tid];
            Xb[256 + tid] = states[(size_t)(b * kN + t) * kM + 256 + tid];
            __syncthreads();
            const int g2 = tid >> 4, l2 = tid & 15;
            for (int r0 = 0; r0 < kM; r0 += 16) {
                int r = r0 + g2;
                const float* wr = W + (size_t)r * kW;
                float a = 0.f;
                for (int k = l2 * 4; k < 1024; k += 64) {
                    float4 w4 = *(const float4*)(wr + k);
                    float4 x4 = *(const float4*)&Xb[k];
                    a = fmaf(w4.x, x4.x, a); a = fmaf(w4.y, x4.y, a);
                    a = fmaf(w4.z, x4.z, a); a = fmaf(w4.w, x4.w, a);
                }
                a += __shfl_xor(a, 1); a += __shfl_xor(a, 2);
                a += __shfl_xor(a, 4); a += __shfl_xor(a, 8);
                if (l2 == 0) Qb[r] = a + attn_b[r];
            }
            __syncthreads();
            qp = Qb;
        }

        // e[s] = sum_m v[m] * tanh(q[m] + C[s][m]); float4, 16 lanes/slot
        const float* crow = &Cs[sidx * kCsStride];
        float acc = 0.f;
#pragma unroll
        for (int j = 0; j < 8; ++j) {
            int m = ml * 4 + j * 64;
            float4 q4 = *(const float4*)(qp + m);
            float4 c4 = *(const float4*)&crow[m];
            float4 v4 = *(const float4*)&vs[m];
            acc = fmaf(v4.x, tanh_fast(q4.x + c4.x), acc);
            acc = fmaf(v4.y, tanh_fast(q4.y + c4.y), acc);
            acc = fmaf(v4.z, tanh_fast(q4.z + c4.z), acc);
            acc = fmaf(v4.w, tanh_fast(q4.w + c4.w), acc);
        }
        acc += __shfl_xor(acc, 1); acc += __shfl_xor(acc, 2);
        acc += __shfl_xor(acc, 4); acc += __shfl_xor(acc, 8);
        if (ml == 0) e_sh[sidx] = acc;
        __syncthreads();

        // wave 0: softmax + empty mask + gumbel + argmax
        if (tid < 64) {
            int s = tid;
            float ev = (s < kS) ? e_sh[s] : -3.0e38f;
            float mx = ev;
            mx = fmaxf(mx, __shfl_xor(mx, 1));
            mx = fmaxf(mx, __shfl_xor(mx, 2));
            mx = fmaxf(mx, __shfl_xor(mx, 4));
            mx = fmaxf(mx, __shfl_xor(mx, 8));
            float w = (s < kS) ? __expf(ev - mx) : 0.f;
            float sm = w;
            sm += __shfl_xor(sm, 1); sm += __shfl_xor(sm, 2);
            sm += __shfl_xor(sm, 4); sm += __shfl_xor(sm, 8);
            w = w / sm;
            w += 10.0f * ((s < kS) ? empty_sh[s] : 0.f);
            float z;
            if (s < kS) {
                float u = gumbel_u[(size_t)(b * kN + t) * kS + s];
                u = fminf(fmaxf(u, 1e-20f), 1.0f);
                float g = -logf(-logf(u) + 1e-20f);
                z = w + g;            // tau = 1.0
            } else z = -3.0e38f;
            float zm = z;
            zm = fmaxf(zm, __shfl_xor(zm, 1));
            zm = fmaxf(zm, __shfl_xor(zm, 2));
            zm = fmaxf(zm, __shfl_xor(zm, 4));
            zm = fmaxf(zm, __shfl_xor(zm, 8));
            unsigned long long bal = __ballot(z == zm) & 0xFFFFull;
            if (s == 0) k_sh = __ffsll(bal) - 1;   // first-max (jnp.argmax)
        }
        __syncthreads();

        const int k = k_sh;
        if (tid < kS) out_log[(size_t)(b * kN + t) * kS + tid] = (tid == k) ? 1.f : 0.f;
        if (tid == 0) {
            float mv = states_mask[b * kN + t];
            wk_sh = (k < kSlots && mv != 0.0f) ? k : -1;
            nz_sh = 0;
        }
        __syncthreads();

        const int wk = wk_sh;
        if (wk >= 0) {
            if (pos < kCap) {
                // cached: C-row copy + precomputed nz flag
                Cs[wk * kCsStride + tid] = cwCache[(size_t)pos * kM + tid];
                Cs[wk * kCsStride + 256 + tid] = cwCache[(size_t)pos * kM + 256 + tid];
                if (tid == 0) {
                    slot_src[wk] = t;
                    empty_sh[wk] = stepNz[pos] ? 0.f : 1.f;
                }
            } else {
                // fallback: inline cw GEMV from staged Xb (dead code normally)
                if (Xb[tid] != 0.f || Xb[256 + tid] != 0.f) nz_sh = 1;
                __syncthreads();
                const int g2 = tid >> 4, l2 = tid & 15;
                for (int r0 = 0; r0 < kM; r0 += 16) {
                    int r = r0 + g2;
                    const float* wr = W + (size_t)r * kW + 1024;
                    float ca = 0.f;
                    for (int k2 = l2 * 4; k2 < kM; k2 += 64) {
                        float4 w4 = *(const float4*)(wr + k2);
                        float4 x4 = *(const float4*)&Xb[k2];
                        ca = fmaf(w4.x, x4.x, ca); ca = fmaf(w4.y, x4.y, ca);
                        ca = fmaf(w4.z, x4.z, ca); ca = fmaf(w4.w, x4.w, ca);
                    }
                    ca += __shfl_xor(ca, 1); ca += __shfl_xor(ca, 2);
                    ca += __shfl_xor(ca, 4); ca += __shfl_xor(ca, 8);
                    if (l2 == 0) Cs[wk * kCsStride + r] = ca;
                }
                __syncthreads();
                if (tid == 0) {
                    slot_src[wk] = t;
                    empty_sh[wk] = nz_sh ? 0.f : 1.f;
                }
            }
        }
        __syncthreads();
    }

    // epilogue: overwrite written slots only (bulk copy already done)
    for (int s = 0; s < kSlots; ++s) {
        int ts = slot_src[s];
        if (ts >= 0) {
            float* dst = out_hm + (size_t)(b * kSlots + s) * kM;
            dst[tid] = states[(size_t)(b * kN + ts) * kM + tid];
            dst[tid + 256] = states[(size_t)(b * kN + ts) * kM + tid + 256];
        }
    }
}

// ---------------------------------------------------------------------------
extern "C" void kernel_launch(void* const* d_in, const int* in_sizes, int n_in,
                              void* d_out, int out_size, void* d_ws, size_t ws_size,
                              hipStream_t stream)
{
    const float* his_mem      = (const float*)d_in[0];
    const float* states       = (const float*)d_in[1];
    const float* states_mask  = (const float*)d_in[2];
    const float* global_trace = (const float*)d_in[3];
    const float* null_mem     = (const float*)d_in[4];
    const float* gumbel_u     = (const float*)d_in[5];
    const float* attn_W       = (const float*)d_in[6];
    const float* attn_b       = (const float*)d_in[7];
    const float* v            = (const float*)d_in[8];

    // ws layout (~40.6 MB):
    //   C0      [4096*512] f32   ( 8 MB)
    //   qCache  [8192*512] f32   (16 MB)
    //   cwCache [8192*512] f32   (16 MB)
    //   cnt[256] i32 | total[16] i32            <- zeroed by one memset
    //   empty0[4096] i32 | ambBatch[256] i32 | stepNz[8192] i32
    //   listPos[32768] i32 | list[32768] u32 | amb[32768] u8
    float* C0 = (float*)d_ws;
    float* qCache = C0 + (size_t)kB * kS * kM;
    float* cwCache = qCache + (size_t)kCap * kM;
    int* cnt = (int*)(cwCache + (size_t)kCap * kM);
    int* total = cnt + kB;
    int* empty0 = total + 16;
    int* ambBatch = empty0 + kB * kS;
    int* stepNz = ambBatch + kB;
    int* listPos = stepNz + kCap;
    unsigned* list = (unsigned*)(listPos + kB * kN);
    unsigned char* amb = (unsigned char*)(list + kB * kN);

    hipMemsetAsync(cnt, 0, (kB + 16) * sizeof(int), stream);
    prep1_k<<<kB, 256, 0, stream>>>(his_mem, null_mem, gumbel_u, (float*)d_out,
                                    empty0, cnt, total, list, listPos, ambBatch,
                                    amb);
    prep2_k<<<2560, 256, 0, stream>>>(attn_W, his_mem, null_mem, states,
                                      global_trace, attn_b, total, ambBatch,
                                      list, C0, qCache, cwCache, stepNz);
    phaseB_k<<<kB, 256, 0, stream>>>(C0, empty0, amb, cnt, listPos, qCache,
                                     cwCache, stepNz, states, states_mask,
                                     gumbel_u, global_trace, attn_W, attn_b, v,
                                     (float*)d_out);
}